// Round 1
// baseline (1217.254 us; speedup 1.0000x reference)
//
#include <hip/hip_runtime.h>
#include <hip/hip_bf16.h>

#define NN 100000      // nodes
#define EE 1600000     // edges
#define GG 1024        // graphs
#define NF 9
#define VV 128
#define HH 128
#define LL 3
#define OUTD 10
#define BN_EPS 1e-5f
#define NB_SCAN 98     // ceil(NN/1024)

// ---------------- CSR build ----------------

__global__ void hist_kernel(const int* __restrict__ dst, int* __restrict__ cnt) {
    int e = blockIdx.x * 256 + threadIdx.x;
    if (e < EE) atomicAdd(&cnt[dst[e]], 1);
}

__global__ void dinv_kernel(const int* __restrict__ cnt, float* __restrict__ dinv) {
    int n = blockIdx.x * 256 + threadIdx.x;
    if (n < NN) dinv[n] = rsqrtf(1.0f + (float)cnt[n]);
}

// block sums over chunks of 1024
__global__ void scanA_kernel(const int* __restrict__ cnt, int* __restrict__ bsum) {
    __shared__ int sh[256];
    int tid = threadIdx.x;
    int base = blockIdx.x * 1024 + tid * 4;
    int s = 0;
#pragma unroll
    for (int i = 0; i < 4; ++i) { int idx = base + i; if (idx < NN) s += cnt[idx]; }
    sh[tid] = s; __syncthreads();
    for (int d = 128; d > 0; d >>= 1) { if (tid < d) sh[tid] += sh[tid + d]; __syncthreads(); }
    if (tid == 0) bsum[blockIdx.x] = sh[0];
}

__global__ void scanB_kernel(int* __restrict__ bsum) {
    if (threadIdx.x == 0 && blockIdx.x == 0) {
        int run = 0;
        for (int i = 0; i < NB_SCAN; ++i) { int t = bsum[i]; bsum[i] = run; run += t; }
    }
}

__global__ void scanC_kernel(const int* __restrict__ cnt, const int* __restrict__ bsum,
                             int* __restrict__ row_ptr, int* __restrict__ cursor) {
    __shared__ int sh[256];
    int tid = threadIdx.x;
    int base = blockIdx.x * 1024 + tid * 4;
    int v[4];
#pragma unroll
    for (int i = 0; i < 4; ++i) { int idx = base + i; v[i] = (idx < NN) ? cnt[idx] : 0; }
    int tsum = v[0] + v[1] + v[2] + v[3];
    sh[tid] = tsum; __syncthreads();
    for (int d = 1; d < 256; d <<= 1) {
        int t = (tid >= d) ? sh[tid - d] : 0;
        __syncthreads();
        sh[tid] += t;
        __syncthreads();
    }
    int excl = sh[tid] - tsum + bsum[blockIdx.x];
#pragma unroll
    for (int i = 0; i < 4; ++i) {
        int idx = base + i;
        if (idx < NN) { row_ptr[idx] = excl; cursor[idx] = excl; }
        excl += v[i];
    }
    if (blockIdx.x == 0 && tid == 0) row_ptr[NN] = EE;
}

__global__ void scatter_kernel(const int* __restrict__ src, const int* __restrict__ dst,
                               const float* __restrict__ dinv, int* __restrict__ cursor,
                               int* __restrict__ col_src, float* __restrict__ col_norm) {
    int e = blockIdx.x * 256 + threadIdx.x;
    if (e >= EE) return;
    int v = dst[e], s = src[e];
    int pos = atomicAdd(&cursor[v], 1);
    col_src[pos] = s;
    col_norm[pos] = dinv[s] * dinv[v];
}

// ---------------- Atom encoder ----------------
// h[n][c] = sum_f emb[f][x[n][f]][c]
__global__ __launch_bounds__(256) void encoder_kernel(const int* __restrict__ x,
                                                      const float* __restrict__ emb,
                                                      float* __restrict__ h) {
    int n = blockIdx.x * 2 + (threadIdx.x >> 7);
    int c = threadIdx.x & 127;
    if (n >= NN) return;
    float s = 0.f;
#pragma unroll
    for (int f = 0; f < NF; ++f) {
        int idx = x[n * NF + f];
        s += emb[(f * VV + idx) * HH + c];
    }
    h[n * HH + c] = s;
}

// ---------------- Dense matmul: hw = h @ W  (W 128x128 in LDS) ----------------
__global__ __launch_bounds__(256) void matmul_kernel(const float* __restrict__ hsrc,
                                                     const float* __restrict__ W,
                                                     float* __restrict__ hwout) {
    __shared__ float lw[HH * HH];  // 64 KB
    for (int i = threadIdx.x; i < HH * HH / 4; i += 256)
        ((float4*)lw)[i] = ((const float4*)W)[i];
    __syncthreads();
    int tid = threadIdx.x;
    int cg = tid & 31;         // cols 4*cg..4*cg+3
    int rg = tid >> 5;         // row group 0..7 (8 rows each)
    int rowbase = blockIdx.x * 64;
    int r0 = rowbase + rg * 8;
    float4 acc[8];
#pragma unroll
    for (int i = 0; i < 8; ++i) acc[i] = make_float4(0, 0, 0, 0);
    const float4* h4 = (const float4*)hsrc;
    const float4* lw4 = (const float4*)lw;
    for (int k4 = 0; k4 < 32; ++k4) {
        float4 a[8];
#pragma unroll
        for (int i = 0; i < 8; ++i) {
            int r = r0 + i;
            a[i] = (r < NN) ? h4[r * 32 + k4] : make_float4(0, 0, 0, 0);
        }
#pragma unroll
        for (int kk = 0; kk < 4; ++kk) {
            float4 w = lw4[(k4 * 4 + kk) * 32 + cg];
#pragma unroll
            for (int i = 0; i < 8; ++i) {
                float av = (kk == 0) ? a[i].x : (kk == 1) ? a[i].y : (kk == 2) ? a[i].z : a[i].w;
                acc[i].x += av * w.x; acc[i].y += av * w.y;
                acc[i].z += av * w.z; acc[i].w += av * w.w;
            }
        }
    }
#pragma unroll
    for (int i = 0; i < 8; ++i) {
        int r = r0 + i;
        if (r < NN) ((float4*)hwout)[r * 32 + cg] = acc[i];
    }
}

// ---------------- CSR aggregate + bias (+ BN + ReLU) ----------------
// hout[v] = sum_in hw[src]*norm + hw[v]*dinv[v]^2 + bias ; optional BN+ReLU
__global__ __launch_bounds__(256) void aggregate_kernel(const float* __restrict__ hw,
    const int* __restrict__ row_ptr, const int* __restrict__ col_src,
    const float* __restrict__ col_norm, const float* __restrict__ dinv,
    const float* __restrict__ bias, const float* __restrict__ gamma,
    const float* __restrict__ beta, const float* __restrict__ rmean,
    const float* __restrict__ rvar, int do_bn, float* __restrict__ hout) {
    int wave = threadIdx.x >> 6;
    int lane = threadIdx.x & 63;
    int v = blockIdx.x * 4 + wave;
    if (v >= NN) return;
    int start = row_ptr[v], end = row_ptr[v + 1];
    const float2* hw2 = (const float2*)hw;
    float ax = 0.f, ay = 0.f;
    for (int j0 = start; j0 < end; j0 += 64) {
        int jj = j0 + lane;
        int s = 0; float nm = 0.f;
        if (jj < end) { s = col_src[jj]; nm = col_norm[jj]; }
        int cnt = min(64, end - j0);
        for (int i = 0; i < cnt; ++i) {
            int ss = __shfl(s, i);
            float nn = __shfl(nm, i);
            float2 r = hw2[ss * 64 + lane];
            ax += nn * r.x; ay += nn * r.y;
        }
    }
    float dv = dinv[v];
    float ns = dv * dv;
    float2 self = hw2[v * 64 + lane];
    ax += ns * self.x; ay += ns * self.y;
    int c0 = 2 * lane, c1 = 2 * lane + 1;
    ax += bias[c0]; ay += bias[c1];
    if (do_bn) {
        float s0 = gamma[c0] * rsqrtf(rvar[c0] + BN_EPS);
        float s1 = gamma[c1] * rsqrtf(rvar[c1] + BN_EPS);
        ax = (ax - rmean[c0]) * s0 + beta[c0];
        ay = (ay - rmean[c1]) * s1 + beta[c1];
        ax = fmaxf(ax, 0.f); ay = fmaxf(ay, 0.f);
    }
    float2 o; o.x = ax; o.y = ay;
    ((float2*)hout)[v * 64 + lane] = o;
}

// ---------------- mean-pool per graph + classifier ----------------
__global__ __launch_bounds__(128) void pool_clf_kernel(const float* __restrict__ h,
    const int* __restrict__ batch, const float* __restrict__ Wc,
    const float* __restrict__ bc, float* __restrict__ out) {
    __shared__ float pooled[HH];
    int g = blockIdx.x;
    int tid = threadIdx.x;
    // lower_bound(batch, key)
    int lo = 0, hi = NN;
    while (lo < hi) { int mid = (lo + hi) >> 1; if (batch[mid] < g) lo = mid + 1; else hi = mid; }
    int start = lo;
    lo = 0; hi = NN;
    int g1 = g + 1;
    while (lo < hi) { int mid = (lo + hi) >> 1; if (batch[mid] < g1) lo = mid + 1; else hi = mid; }
    int end = lo;
    float s = 0.f;
    for (int n = start; n < end; ++n) s += h[n * HH + tid];
    float cntf = (float)(end - start);
    pooled[tid] = s / fmaxf(cntf, 1.0f);
    __syncthreads();
    if (tid < OUTD) {
        float acc = bc[tid];
#pragma unroll 16
        for (int c = 0; c < HH; ++c) acc += pooled[c] * Wc[c * OUTD + tid];
        out[g * OUTD + tid] = acc;
    }
}

extern "C" void kernel_launch(void* const* d_in, const int* in_sizes, int n_in,
                              void* d_out, int out_size, void* d_ws, size_t ws_size,
                              hipStream_t stream) {
    const int*   x      = (const int*)d_in[0];
    const int*   eidx   = (const int*)d_in[1];
    const int*   batch  = (const int*)d_in[2];
    const float* emb    = (const float*)d_in[3];
    const float* Ws     = (const float*)d_in[4];
    const float* bs     = (const float*)d_in[5];
    const float* gamma  = (const float*)d_in[6];
    const float* beta   = (const float*)d_in[7];
    const float* rmean  = (const float*)d_in[8];
    const float* rvar   = (const float*)d_in[9];
    const float* Wclf   = (const float*)d_in[10];
    const float* bclf   = (const float*)d_in[11];
    float* out = (float*)d_out;

    const int* e_src = eidx;
    const int* e_dst = eidx + EE;

    // workspace carve-out (256B aligned)
    char* ws = (char*)d_ws;
    size_t off = 0;
    auto take = [&](size_t bytes) -> void* {
        void* p = ws + off;
        off = (off + bytes + 255) & ~(size_t)255;
        return p;
    };
    float* dinv     = (float*)take((size_t)NN * 4);
    int*   cnt      = (int*)  take((size_t)NN * 4);
    int*   row_ptr  = (int*)  take((size_t)(NN + 1) * 4);
    int*   cursor   = (int*)  take((size_t)NN * 4);
    int*   bsum     = (int*)  take((size_t)NB_SCAN * 4);
    int*   col_src  = (int*)  take((size_t)EE * 4);
    float* col_norm = (float*)take((size_t)EE * 4);
    float* hbuf     = (float*)take((size_t)NN * HH * 4);
    float* hwbuf    = (float*)take((size_t)NN * HH * 4);

    hipMemsetAsync(cnt, 0, (size_t)NN * 4, stream);

    hist_kernel<<<(EE + 255) / 256, 256, 0, stream>>>(e_dst, cnt);
    dinv_kernel<<<(NN + 255) / 256, 256, 0, stream>>>(cnt, dinv);
    scanA_kernel<<<NB_SCAN, 256, 0, stream>>>(cnt, bsum);
    scanB_kernel<<<1, 64, 0, stream>>>(bsum);
    scanC_kernel<<<NB_SCAN, 256, 0, stream>>>(cnt, bsum, row_ptr, cursor);
    scatter_kernel<<<(EE + 255) / 256, 256, 0, stream>>>(e_src, e_dst, dinv, cursor,
                                                         col_src, col_norm);
    encoder_kernel<<<(NN + 1) / 2, 256, 0, stream>>>(x, emb, hbuf);

    for (int i = 0; i < LL; ++i) {
        matmul_kernel<<<(NN + 63) / 64, 256, 0, stream>>>(hbuf, Ws + (size_t)i * HH * HH, hwbuf);
        int do_bn = (i < LL - 1) ? 1 : 0;
        int pi = do_bn ? i : 0;  // BN params unused when do_bn=0
        aggregate_kernel<<<(NN + 3) / 4, 256, 0, stream>>>(
            hwbuf, row_ptr, col_src, col_norm, dinv,
            bs + (size_t)i * HH, gamma + (size_t)pi * HH, beta + (size_t)pi * HH,
            rmean + (size_t)pi * HH, rvar + (size_t)pi * HH, do_bn, hbuf);
    }

    pool_clf_kernel<<<GG, 128, 0, stream>>>(hbuf, batch, Wclf, bclf, out);
}

// Round 2
// 835.581 us; speedup vs baseline: 1.4568x; 1.4568x over previous
//
#include <hip/hip_runtime.h>
#include <hip/hip_bf16.h>

#define NN 100000      // nodes
#define EE 1600000     // edges
#define GG 1024        // graphs
#define NF 9
#define VV 128
#define HH 128
#define LL 3
#define OUTD 10
#define BN_EPS 1e-5f
#define NB_SCAN 98     // ceil(NN/1024)

typedef __attribute__((ext_vector_type(8))) short short8;   // 8 bf16 = 4 VGPRs
typedef __attribute__((ext_vector_type(4))) float f32x4;

__device__ inline unsigned short f2bf(float x) {          // RNE f32 -> bf16 bits
    unsigned u = __float_as_uint(x);
    unsigned r = (u + 0x7fffu + ((u >> 16) & 1u)) >> 16;
    return (unsigned short)r;
}
__device__ inline float bf2f(unsigned short b) { return __uint_as_float(((unsigned)b) << 16); }

// ---------------- CSR build ----------------

__global__ void hist_kernel(const int* __restrict__ dst, int* __restrict__ cnt) {
    int e = blockIdx.x * 256 + threadIdx.x;
    if (e < EE) atomicAdd(&cnt[dst[e]], 1);
}

__global__ void dinv_kernel(const int* __restrict__ cnt, float* __restrict__ dinv) {
    int n = blockIdx.x * 256 + threadIdx.x;
    if (n < NN) dinv[n] = rsqrtf(1.0f + (float)cnt[n]);
}

__global__ void scanA_kernel(const int* __restrict__ cnt, int* __restrict__ bsum) {
    __shared__ int sh[256];
    int tid = threadIdx.x;
    int base = blockIdx.x * 1024 + tid * 4;
    int s = 0;
#pragma unroll
    for (int i = 0; i < 4; ++i) { int idx = base + i; if (idx < NN) s += cnt[idx]; }
    sh[tid] = s; __syncthreads();
    for (int d = 128; d > 0; d >>= 1) { if (tid < d) sh[tid] += sh[tid + d]; __syncthreads(); }
    if (tid == 0) bsum[blockIdx.x] = sh[0];
}

__global__ void scanB_kernel(int* __restrict__ bsum) {
    if (threadIdx.x == 0 && blockIdx.x == 0) {
        int run = 0;
        for (int i = 0; i < NB_SCAN; ++i) { int t = bsum[i]; bsum[i] = run; run += t; }
    }
}

__global__ void scanC_kernel(const int* __restrict__ cnt, const int* __restrict__ bsum,
                             int* __restrict__ row_ptr, int* __restrict__ cursor) {
    __shared__ int sh[256];
    int tid = threadIdx.x;
    int base = blockIdx.x * 1024 + tid * 4;
    int v[4];
#pragma unroll
    for (int i = 0; i < 4; ++i) { int idx = base + i; v[i] = (idx < NN) ? cnt[idx] : 0; }
    int tsum = v[0] + v[1] + v[2] + v[3];
    sh[tid] = tsum; __syncthreads();
    for (int d = 1; d < 256; d <<= 1) {
        int t = (tid >= d) ? sh[tid - d] : 0;
        __syncthreads();
        sh[tid] += t;
        __syncthreads();
    }
    int excl = sh[tid] - tsum + bsum[blockIdx.x];
#pragma unroll
    for (int i = 0; i < 4; ++i) {
        int idx = base + i;
        if (idx < NN) { row_ptr[idx] = excl; cursor[idx] = excl; }
        excl += v[i];
    }
    if (blockIdx.x == 0 && tid == 0) row_ptr[NN] = EE;
}

__global__ void scatter_kernel(const int* __restrict__ src, const int* __restrict__ dst,
                               const float* __restrict__ dinv, int* __restrict__ cursor,
                               int* __restrict__ col_src, float* __restrict__ col_norm) {
    int e = blockIdx.x * 256 + threadIdx.x;
    if (e >= EE) return;
    int v = dst[e], s = src[e];
    int pos = atomicAdd(&cursor[v], 1);
    col_src[pos] = s;
    col_norm[pos] = dinv[s] * dinv[v];
}

// ---------------- W^T hi/lo conversion (once per layer) ----------------
__global__ void wconv_kernel(const float* __restrict__ Ws,
                             unsigned short* __restrict__ WThi,
                             unsigned short* __restrict__ WTlo) {
    int layer = blockIdx.x;
    const float* W = Ws + (size_t)layer * HH * HH;
    unsigned short* th = WThi + (size_t)layer * HH * HH;
    unsigned short* tl = WTlo + (size_t)layer * HH * HH;
    for (int id = threadIdx.x; id < HH * HH; id += 256) {
        int k = id >> 7, n = id & 127;
        float w = W[id];
        unsigned short hi = f2bf(w);
        float lo = w - bf2f(hi);
        th[n * HH + k] = hi;        // transposed: [n][k], k-contiguous for B-frags
        tl[n * HH + k] = f2bf(lo);
    }
}

// ---------------- Atom encoder: h -> bf16 hi/lo planes ----------------
__global__ __launch_bounds__(256) void encoder_kernel(const int* __restrict__ x,
                                                      const float* __restrict__ emb,
                                                      unsigned short* __restrict__ hhi,
                                                      unsigned short* __restrict__ hlo) {
    int n = blockIdx.x * 2 + (threadIdx.x >> 7);
    int c = threadIdx.x & 127;
    if (n >= NN) return;
    float s = 0.f;
#pragma unroll
    for (int f = 0; f < NF; ++f) {
        int idx = x[n * NF + f];
        s += emb[(f * VV + idx) * HH + c];
    }
    unsigned short hi = f2bf(s);
    hhi[n * HH + c] = hi;
    hlo[n * HH + c] = f2bf(s - bf2f(hi));
}

// ---------------- MFMA matmul: hw = h @ W (bf16 hi/lo x3, fp32-accurate) ----------------
// 128 rows/block, 4 waves, each wave 32 rows x 128 cols. No LDS.
__global__ __launch_bounds__(256) void matmul_mfma_kernel(
        const unsigned short* __restrict__ hhi, const unsigned short* __restrict__ hlo,
        const unsigned short* __restrict__ WThi, const unsigned short* __restrict__ WTlo,
        float* __restrict__ hw) {
    int wave = threadIdx.x >> 6, lane = threadIdx.x & 63;
    int quad = lane >> 4, m = lane & 15;
    int rowbase = blockIdx.x * 128 + wave * 32;
    if (rowbase >= NN) return;   // NN % 32 == 0, so tiles are all-or-nothing; no syncthreads in kernel
    f32x4 acc[2][8] = {};
    int kq = quad * 8;
#pragma unroll
    for (int t = 0; t < 4; ++t) {
        int k0 = t * 32 + kq;
        short8 a0h = *(const short8*)(hhi + (size_t)(rowbase + m) * HH + k0);
        short8 a0l = *(const short8*)(hlo + (size_t)(rowbase + m) * HH + k0);
        short8 a1h = *(const short8*)(hhi + (size_t)(rowbase + 16 + m) * HH + k0);
        short8 a1l = *(const short8*)(hlo + (size_t)(rowbase + 16 + m) * HH + k0);
#pragma unroll
        for (int ct = 0; ct < 8; ++ct) {
            short8 bh = *(const short8*)(WThi + (size_t)(ct * 16 + m) * HH + k0);
            short8 bl = *(const short8*)(WTlo + (size_t)(ct * 16 + m) * HH + k0);
            acc[0][ct] = __builtin_amdgcn_mfma_f32_16x16x32_bf16(a0h, bh, acc[0][ct], 0, 0, 0);
            acc[0][ct] = __builtin_amdgcn_mfma_f32_16x16x32_bf16(a0l, bh, acc[0][ct], 0, 0, 0);
            acc[0][ct] = __builtin_amdgcn_mfma_f32_16x16x32_bf16(a0h, bl, acc[0][ct], 0, 0, 0);
            acc[1][ct] = __builtin_amdgcn_mfma_f32_16x16x32_bf16(a1h, bh, acc[1][ct], 0, 0, 0);
            acc[1][ct] = __builtin_amdgcn_mfma_f32_16x16x32_bf16(a1l, bh, acc[1][ct], 0, 0, 0);
            acc[1][ct] = __builtin_amdgcn_mfma_f32_16x16x32_bf16(a1h, bl, acc[1][ct], 0, 0, 0);
        }
    }
    // C/D layout: col = lane&15, row = quad*4 + reg
#pragma unroll
    for (int ct = 0; ct < 8; ++ct) {
        int col = ct * 16 + m;
#pragma unroll
        for (int rt = 0; rt < 2; ++rt) {
            int r0 = rowbase + rt * 16 + quad * 4;
#pragma unroll
            for (int reg = 0; reg < 4; ++reg)
                hw[(size_t)(r0 + reg) * HH + col] = acc[rt][ct][reg];
        }
    }
}

// ---------------- CSR aggregate + bias (+ BN + ReLU) -> bf16 hi/lo planes ----------------
// Wave per node; two 32-lane halves each gather a different edge's float4 row (2x MLP).
__global__ __launch_bounds__(256) void aggregate_kernel(const float* __restrict__ hw,
    const int* __restrict__ row_ptr, const int* __restrict__ col_src,
    const float* __restrict__ col_norm, const float* __restrict__ dinv,
    const float* __restrict__ bias, const float* __restrict__ gamma,
    const float* __restrict__ beta, const float* __restrict__ rmean,
    const float* __restrict__ rvar, int do_bn,
    unsigned short* __restrict__ hhi, unsigned short* __restrict__ hlo) {
    int wave = threadIdx.x >> 6;
    int lane = threadIdx.x & 63;
    int half = lane >> 5;
    int c = lane & 31;          // float4 group: cols 4c..4c+3
    int v = blockIdx.x * 4 + wave;
    if (v >= NN) return;
    int start = row_ptr[v], end = row_ptr[v + 1];
    const float4* hw4 = (const float4*)hw;
    float ax = 0.f, ay = 0.f, az = 0.f, aw = 0.f;
    for (int j0 = start; j0 < end; j0 += 64) {
        int jj = j0 + lane;
        int s = 0; float nm = 0.f;
        if (jj < end) { s = col_src[jj]; nm = col_norm[jj]; }
        int mm = min(64, end - j0);
        int pairs = mm >> 1;
        for (int p = 0; p < pairs; ++p) {
            int ss = __shfl(s, 2 * p + half);
            float nn = __shfl(nm, 2 * p + half);
            float4 r = hw4[(size_t)ss * 32 + c];
            ax += nn * r.x; ay += nn * r.y; az += nn * r.z; aw += nn * r.w;
        }
        if (mm & 1) {
            int ss = __shfl(s, mm - 1);
            float nn = __shfl(nm, mm - 1);
            if (half) nn = 0.f;
            float4 r = hw4[(size_t)ss * 32 + c];
            ax += nn * r.x; ay += nn * r.y; az += nn * r.z; aw += nn * r.w;
        }
    }
    // cross-half reduce
    ax += __shfl_xor(ax, 32); ay += __shfl_xor(ay, 32);
    az += __shfl_xor(az, 32); aw += __shfl_xor(aw, 32);
    if (half == 0) {
        float dv = dinv[v];
        float ns = dv * dv;
        float4 self = hw4[(size_t)v * 32 + c];
        float4 bb = ((const float4*)bias)[c];
        ax += ns * self.x + bb.x; ay += ns * self.y + bb.y;
        az += ns * self.z + bb.z; aw += ns * self.w + bb.w;
        if (do_bn) {
            float4 gm = ((const float4*)gamma)[c];
            float4 bt = ((const float4*)beta)[c];
            float4 rm = ((const float4*)rmean)[c];
            float4 rv = ((const float4*)rvar)[c];
            ax = fmaxf((ax - rm.x) * (gm.x * rsqrtf(rv.x + BN_EPS)) + bt.x, 0.f);
            ay = fmaxf((ay - rm.y) * (gm.y * rsqrtf(rv.y + BN_EPS)) + bt.y, 0.f);
            az = fmaxf((az - rm.z) * (gm.z * rsqrtf(rv.z + BN_EPS)) + bt.z, 0.f);
            aw = fmaxf((aw - rm.w) * (gm.w * rsqrtf(rv.w + BN_EPS)) + bt.w, 0.f);
        }
        ushort4 oh, ol;
        oh.x = f2bf(ax); ol.x = f2bf(ax - bf2f(oh.x));
        oh.y = f2bf(ay); ol.y = f2bf(ay - bf2f(oh.y));
        oh.z = f2bf(az); ol.z = f2bf(az - bf2f(oh.z));
        oh.w = f2bf(aw); ol.w = f2bf(aw - bf2f(oh.w));
        ((ushort4*)hhi)[(size_t)v * 32 + c] = oh;
        ((ushort4*)hlo)[(size_t)v * 32 + c] = ol;
    }
}

// ---------------- mean-pool per graph + classifier ----------------
__global__ __launch_bounds__(128) void pool_clf_kernel(const unsigned short* __restrict__ hhi,
    const unsigned short* __restrict__ hlo,
    const int* __restrict__ batch, const float* __restrict__ Wc,
    const float* __restrict__ bc, float* __restrict__ out) {
    __shared__ float pooled[HH];
    int g = blockIdx.x;
    int tid = threadIdx.x;
    int lo = 0, hi = NN;
    while (lo < hi) { int mid = (lo + hi) >> 1; if (batch[mid] < g) lo = mid + 1; else hi = mid; }
    int start = lo;
    lo = 0; hi = NN;
    int g1 = g + 1;
    while (lo < hi) { int mid = (lo + hi) >> 1; if (batch[mid] < g1) lo = mid + 1; else hi = mid; }
    int end = lo;
    float s = 0.f;
    for (int n = start; n < end; ++n)
        s += bf2f(hhi[(size_t)n * HH + tid]) + bf2f(hlo[(size_t)n * HH + tid]);
    float cntf = (float)(end - start);
    pooled[tid] = s / fmaxf(cntf, 1.0f);
    __syncthreads();
    if (tid < OUTD) {
        float acc = bc[tid];
#pragma unroll 16
        for (int c = 0; c < HH; ++c) acc += pooled[c] * Wc[c * OUTD + tid];
        out[g * OUTD + tid] = acc;
    }
}

extern "C" void kernel_launch(void* const* d_in, const int* in_sizes, int n_in,
                              void* d_out, int out_size, void* d_ws, size_t ws_size,
                              hipStream_t stream) {
    const int*   x      = (const int*)d_in[0];
    const int*   eidx   = (const int*)d_in[1];
    const int*   batch  = (const int*)d_in[2];
    const float* emb    = (const float*)d_in[3];
    const float* Ws     = (const float*)d_in[4];
    const float* bs     = (const float*)d_in[5];
    const float* gamma  = (const float*)d_in[6];
    const float* beta   = (const float*)d_in[7];
    const float* rmean  = (const float*)d_in[8];
    const float* rvar   = (const float*)d_in[9];
    const float* Wclf   = (const float*)d_in[10];
    const float* bclf   = (const float*)d_in[11];
    float* out = (float*)d_out;

    const int* e_src = eidx;
    const int* e_dst = eidx + EE;

    char* ws = (char*)d_ws;
    size_t off = 0;
    auto take = [&](size_t bytes) -> void* {
        void* p = ws + off;
        off = (off + bytes + 255) & ~(size_t)255;
        return p;
    };
    float* dinv     = (float*)take((size_t)NN * 4);
    int*   cnt      = (int*)  take((size_t)NN * 4);
    int*   row_ptr  = (int*)  take((size_t)(NN + 1) * 4);
    int*   cursor   = (int*)  take((size_t)NN * 4);
    int*   bsum     = (int*)  take((size_t)NB_SCAN * 4);
    int*   col_src  = (int*)  take((size_t)EE * 4);
    float* col_norm = (float*)take((size_t)EE * 4);
    unsigned short* hhi  = (unsigned short*)take((size_t)NN * HH * 2);
    unsigned short* hlo  = (unsigned short*)take((size_t)NN * HH * 2);
    float* hwbuf    = (float*)take((size_t)NN * HH * 4);
    unsigned short* WThi = (unsigned short*)take((size_t)LL * HH * HH * 2);
    unsigned short* WTlo = (unsigned short*)take((size_t)LL * HH * HH * 2);

    hipMemsetAsync(cnt, 0, (size_t)NN * 4, stream);

    hist_kernel<<<(EE + 255) / 256, 256, 0, stream>>>(e_dst, cnt);
    dinv_kernel<<<(NN + 255) / 256, 256, 0, stream>>>(cnt, dinv);
    scanA_kernel<<<NB_SCAN, 256, 0, stream>>>(cnt, bsum);
    scanB_kernel<<<1, 64, 0, stream>>>(bsum);
    scanC_kernel<<<NB_SCAN, 256, 0, stream>>>(cnt, bsum, row_ptr, cursor);
    scatter_kernel<<<(EE + 255) / 256, 256, 0, stream>>>(e_src, e_dst, dinv, cursor,
                                                         col_src, col_norm);
    wconv_kernel<<<LL, 256, 0, stream>>>(Ws, WThi, WTlo);
    encoder_kernel<<<(NN + 1) / 2, 256, 0, stream>>>(x, emb, hhi, hlo);

    for (int i = 0; i < LL; ++i) {
        matmul_mfma_kernel<<<(NN + 127) / 128, 256, 0, stream>>>(
            hhi, hlo, WThi + (size_t)i * HH * HH, WTlo + (size_t)i * HH * HH, hwbuf);
        int do_bn = (i < LL - 1) ? 1 : 0;
        int pi = do_bn ? i : 0;
        aggregate_kernel<<<(NN + 3) / 4, 256, 0, stream>>>(
            hwbuf, row_ptr, col_src, col_norm, dinv,
            bs + (size_t)i * HH, gamma + (size_t)pi * HH, beta + (size_t)pi * HH,
            rmean + (size_t)pi * HH, rvar + (size_t)pi * HH, do_bn, hhi, hlo);
    }

    pool_clf_kernel<<<GG, 128, 0, stream>>>(hhi, hlo, batch, Wclf, bclf, out);
}